// Round 14
// baseline (251.192 us; speedup 1.0000x reference)
//
#include <hip/hip_runtime.h>
#include <math.h>

// Problem constants (reference: B,P,NTIME,NLATENT,NSPATIAL = 4,2,16,32,2048)
#define NB 4
#define NP 2
#define NT 16
#define NC 32
#define NX 2048

// ---------------------------------------------------------------------------
// R25 = R22 (best: 87us site, absmax 2.4e-7, reg-h, no prefetch) with the
// macro-expansion treatment COMPLETED: stages 1+2 and 3 fully expanded with
// literal M (R22 only did stage 0). R24's A/B proved explicit frag prefetch
// is NEGATIVE (93 vs 87us — compiler already schedules loads; extra live
// ranges hurt). Revised latency theory: the exposed latency is the serial
// intra-iteration chain MFMA->dot->shfl->sqrt->(pe*U) inside the unroll-1
// loops; expansion lets the scheduler overlap independent e-pairs.
// __launch_bounds__(256,4) caps VGPR at 128 (occupancy guard; watch
// WRITE_SIZE for spills). Inner r-loops keep the R20/R22-proven
// literal-after-unroll pattern (promotion-safe, rule #20).
// Engine: 32x32x16 MFMA, stacked e-pairs, 3-MFMA split (MhVh+MhVl+MlVh).
// C-layout HW-verified: col=lane&31, row=(reg&3)+8(reg>>2)+4(lane>>5).
// Ledger: readlane=VALU-bound(R11); s_load=latency-bound(R13); LDS
// broadcast=DS-bound(R15); aliased permlane32_swap=WRONG(R17); unroll-
// pragma outer-idx arrays=PROMOTED->macro literal (R21/R22); 1-wave
// blocks=occupancy-poison(R23); explicit frag prefetch=NEGATIVE(R24);
// total-site gap ~75us = fixed overhead+precompute floor.
// ---------------------------------------------------------------------------

typedef _Float16 f16x8 __attribute__((ext_vector_type(8)));
typedef float f32x16 __attribute__((ext_vector_type(16)));

__device__ __forceinline__ unsigned short f16hi_bits(float v) {
    _Float16 h = (_Float16)v;
    return __builtin_bit_cast(unsigned short, h);
}
__device__ __forceinline__ unsigned short f16lo_bits(float v) {
    _Float16 h = (_Float16)v;
    _Float16 l = (_Float16)(v - (float)h);
    return __builtin_bit_cast(unsigned short, l);
}
__device__ __forceinline__ f16x8 frag_cast(uint4 u) {
    return __builtin_bit_cast(f16x8, u);
}
__device__ __forceinline__ float sqrt_act(float v) {
    const float s = __builtin_amdgcn_sqrtf(__builtin_fabsf(v));
    return copysignf(s, v);
}
__device__ __forceinline__ f32x16 zero16() {
    f32x16 z;
#pragma unroll
    for (int i = 0; i < 16; ++i) z[i] = 0.f;
    return z;
}

// ---------------------------------------------------------------------------
// Precompute (R21/R22, validated). Pair-frag: pair m holds A-rows 0-15 =
// matrix 2m, 16-31 = matrix 2m+1; 128 uint4 = [hi 64][lo 64]; lane:
// row=lane&31, k=(lane>>5)*8+j.
//  blocks [0,512)   : G0, one e per block (c=b>>4, e=b&15)
//  blocks [512,528) : G1, one e per block
//  blocks [528,536) : M1t pairs (dec+Q1 LDS-staged)
//  blocks [536,792) : M2 pairs  (dec+Q0-col LDS-staged)
//  block  792       : zero out[256]
// ---------------------------------------------------------------------------
__device__ void g_compute(const float* __restrict__ K,
                          const float* __restrict__ V,
                          const float* __restrict__ enc,
                          int cstride, int c, int e, int tid,
                          float* sK, float* sV, float* sE, float* sW,
                          float* outG) {
    {
        const int t = tid >> 4, A = tid & 15;
        sK[tid] = K[(t * 16 + A) * cstride + c];
        sV[tid] = V[(t * 16 + A) * cstride + c];
        sE[tid] = enc[(e * 16 + t) * 16 + A];
    }
    __syncthreads();
    {   // W[t,B] = sum_T enc[e,t,T] * V[T,B,c]
        const int t = tid >> 4, Bi = tid & 15;
        float acc = 0.f;
#pragma unroll
        for (int T = 0; T < 16; ++T) acc += sE[t * 16 + T] * sV[T * 16 + Bi];
        sW[tid] = acc;
    }
    __syncthreads();
    {   // G[A,B] = sum_t K[t,A,c] * W[t,B]   (quadratic form: orientation-immune)
        const int A = tid >> 4, Bi = tid & 15;
        float acc = 0.f;
#pragma unroll
        for (int t = 0; t < 16; ++t) acc += sK[t * 16 + A] * sW[t * 16 + Bi];
        outG[tid] = acc;
    }
    __syncthreads();
}

__device__ void emit_half(const float* sG, uint4* __restrict__ dstPair,
                          int half, int tid) {
    if (tid < 64) {
        const int row = tid & 15, g = (tid >> 4) & 1, part = tid >> 5;
        unsigned dw[4];
#pragma unroll
        for (int d = 0; d < 4; ++d) {
            const float v0 = sG[row * 16 + g * 8 + 2 * d];
            const float v1 = sG[row * 16 + g * 8 + 2 * d + 1];
            const unsigned short s0 = part ? f16lo_bits(v0) : f16hi_bits(v0);
            const unsigned short s1 = part ? f16lo_bits(v1) : f16hi_bits(v1);
            dw[d] = (unsigned)s0 | ((unsigned)s1 << 16);
        }
        dstPair[part * 64 + g * 32 + 16 * half + row] =
            make_uint4(dw[0], dw[1], dw[2], dw[3]);
    }
}

__global__ __launch_bounds__(256) void precompute_all(
    const float* __restrict__ K0, const float* __restrict__ V0,
    const float* __restrict__ K1, const float* __restrict__ V1,
    const float* __restrict__ Q0, const float* __restrict__ Q1,
    const float* __restrict__ enc, const float* __restrict__ dec,
    uint4* __restrict__ AF0, uint4* __restrict__ AFG1,
    uint4* __restrict__ AFM1, uint4* __restrict__ AFM2,
    float* __restrict__ out) {
    __shared__ float sK[256], sV[256], sE[256], sW[256], sG[256];
    __shared__ float sDec[4096], sQ[256];
    const int b = blockIdx.x, tid = threadIdx.x;
    if (b < 512) {
        const int c = b >> 4, e = b & 15;
        g_compute(K0, V0, enc, NC, c, e, tid, sK, sV, sE, sW, sG);
        emit_half(sG, AF0 + (c * 8 + (e >> 1)) * 128, e & 1, tid);
    } else if (b < 528) {
        const int e = b - 512;
        g_compute(K1, V1, enc, 1, 0, e, tid, sK, sV, sE, sW, sG);
        emit_half(sG, AFG1 + (e >> 1) * 128, e & 1, tid);
    } else if (b < 536) {
        // M1t[e][E][T] = sum_t Q1[t,T]*dec[e,t,E]; pair rows=E, k=T
        const int m = b - 528;
#pragma unroll
        for (int i = tid; i < 4096; i += 256) sDec[i] = dec[i];
        sQ[tid] = Q1[tid];
        __syncthreads();
        if (tid < 128) {
            const int part = tid >> 6, lane = tid & 63;
            const int row32 = lane & 31, g = lane >> 5;
            const int e = 2 * m + (row32 >> 4), E = row32 & 15;
            unsigned dw[4];
#pragma unroll
            for (int d = 0; d < 4; ++d) {
                unsigned short s01[2];
#pragma unroll
                for (int hh = 0; hh < 2; ++hh) {
                    const int T = g * 8 + 2 * d + hh;
                    float acc = 0.f;
#pragma unroll
                    for (int t = 0; t < 16; ++t)
                        acc += sQ[t * 16 + T] * sDec[(e * 16 + t) * 16 + E];
                    s01[hh] = part ? f16lo_bits(acc) : f16hi_bits(acc);
                }
                dw[d] = (unsigned)s01[0] | ((unsigned)s01[1] << 16);
            }
            AFM1[m * 128 + part * 64 + lane] = make_uint4(dw[0], dw[1], dw[2], dw[3]);
        }
    } else if (b < 792) {
        // M2[c][T][A][E] = sum_t Q0[t,A,c]*dec[E,t,T]; pair rows=A (T-pair), k=E
        const int idx = b - 536;
        const int c = idx >> 3, m = idx & 7;
#pragma unroll
        for (int i = tid; i < 4096; i += 256) sDec[i] = dec[i];
        sQ[tid] = Q0[tid * NC + c];            // tid = t*16+A
        __syncthreads();
        if (tid < 128) {
            const int part = tid >> 6, lane = tid & 63;
            const int row32 = lane & 31, g = lane >> 5;
            const int T = 2 * m + (row32 >> 4), A = row32 & 15;
            unsigned dw[4];
#pragma unroll
            for (int d = 0; d < 4; ++d) {
                unsigned short s01[2];
#pragma unroll
                for (int hh = 0; hh < 2; ++hh) {
                    const int E = g * 8 + 2 * d + hh;
                    float acc = 0.f;
#pragma unroll
                    for (int t = 0; t < 16; ++t)
                        acc += sQ[t * 16 + A] * sDec[(E * 16 + t) * 16 + T];
                    s01[hh] = part ? f16lo_bits(acc) : f16hi_bits(acc);
                }
                dw[d] = (unsigned)s01[0] | ((unsigned)s01[1] << 16);
            }
            AFM2[(c * 8 + m) * 128 + part * 64 + lane] =
                make_uint4(dw[0], dw[1], dw[2], dw[3]);
        }
    } else {
        out[tid] = 0.f;   // out = NB*NP*NC = 256 floats
    }
}

// ---------------------------------------------------------------------------
// Main kernel: 4 waves/block (256 thr), one wave = 32 x-sites (col=lane&31)
// of one (bp,c). grid = 4096; consecutive blocks share (bp,c) -> frag
// tables L2/L1-hot. Register-h; ALL THREE stage loops macro-expanded with
// literal M (scheduler can overlap independent e-pair chains). No explicit
// prefetch (R24: negative). LDS = red[16B] only. VGPR cap 128 via
// __launch_bounds__(256,4).
// ---------------------------------------------------------------------------
__global__ __launch_bounds__(256, 4) void site_kernel(
    const float* __restrict__ x,
    const float* __restrict__ a,
    const float* __restrict__ w,
    const uint4* __restrict__ AF0,
    const uint4* __restrict__ AFG1,
    const uint4* __restrict__ AFM1,
    const uint4* __restrict__ AFM2,
    float* __restrict__ out) {
    __shared__ float red[4];

    const int tid = threadIdx.x;
    const int lane = tid & 63, wid = tid >> 6;
    const int col = lane & 31, g = lane >> 5;
    const bool g0 = (g == 0);
    const int bid = blockIdx.x;
    const int xg = bid & 15;
    const int c  = (bid >> 4) & 31;
    const int bp = bid >> 9;
    const int xA = xg * 128 + wid * 32 + col;
    const float* xb = x + (bp * NT * NC + c) * NX;

    // ---- X: B-pack k-rows g*8+j (f16 hi/lo) + C-rows A(r)=(r&3)+8(r>>2)+4g ----
    f16x8 Xh, Xl;
    float XC[8];
#pragma unroll
    for (int j = 0; j < 8; ++j) {
        const float v = xb[(g * 8 + j) * NC * NX + xA];
        const _Float16 hv = (_Float16)v;
        Xh[j] = hv; Xl[j] = (_Float16)(v - (float)hv);
    }
#pragma unroll
    for (int r = 0; r < 8; ++r) {
        const int A = (r & 3) + 8 * (r >> 2) + 4 * g;
        XC[r] = xb[A * NC * NX + xA];
    }

    const f32x16 Z0 = zero16();    // shared accumulator-zero (one init)

    // ======== stage 0: h[e] = sqrt_act( X^T G0[c,e] X ), e-pairs ========
    float h[16];
    {
        const uint4* p0 = AF0 + (c * 8) * 128 + lane;
#define S0_ITER(M)                                                          \
        do {                                                                \
            const f16x8 Ah = frag_cast(p0[(M) * 128]);                      \
            const f16x8 Al = frag_cast(p0[(M) * 128 + 64]);                 \
            f32x16 C = __builtin_amdgcn_mfma_f32_32x32x16_f16(Ah, Xh, Z0, 0, 0, 0); \
            C = __builtin_amdgcn_mfma_f32_32x32x16_f16(Ah, Xl, C, 0, 0, 0); \
            C = __builtin_amdgcn_mfma_f32_32x32x16_f16(Al, Xh, C, 0, 0, 0); \
            float se = 0.f, so = 0.f;                                       \
            _Pragma("unroll")                                               \
            for (int r = 0; r < 8; ++r) {                                   \
                se += XC[r] * C[r];                                         \
                so += XC[r] * C[r + 8];                                     \
            }                                                               \
            se += __shfl_xor(se, 32);                                       \
            so += __shfl_xor(so, 32);                                       \
            h[2 * (M)]     = sqrt_act(se);                                  \
            h[2 * (M) + 1] = sqrt_act(so);                                  \
        } while (0)
        S0_ITER(0); S0_ITER(1); S0_ITER(2); S0_ITER(3);
        S0_ITER(4); S0_ITER(5); S0_ITER(6); S0_ITER(7);
#undef S0_ITER
    }

    // ---- h packs from registers: literal indices via macro expansion ----
    f16x8 hH, hL;
    float hC[8];
#define HPK(J)                                                              \
    {                                                                       \
        const float v = g0 ? h[J] : h[(J) + 8];        /* k = g*8+J */      \
        const _Float16 hv = (_Float16)v;                                    \
        hH[J] = hv; hL[J] = (_Float16)(v - (float)hv);                      \
    }
    HPK(0) HPK(1) HPK(2) HPK(3) HPK(4) HPK(5) HPK(6) HPK(7)
#undef HPK
#define HCK(R, BASE) hC[R] = g0 ? h[BASE] : h[(BASE) + 4];
    HCK(0, 0) HCK(1, 1) HCK(2, 2) HCK(3, 3)
    HCK(4, 8) HCK(5, 9) HCK(6, 10) HCK(7, 11)
#undef HCK

    // ======== stages 1+2 (e-pairs), MACRO-EXPANDED:
    //   pe = a[e,x]*sqrt_act(h^T G1[e] h);
    //   b2[E] += pe_even*U_even[E] + pe_odd*U_odd[E], U = M1t-pair . h
    float b2[8];
#pragma unroll
    for (int r = 0; r < 8; ++r) b2[r] = 0.f;
    {
        const uint4* pG = AFG1 + lane;
        const uint4* pM = AFM1 + lane;
        const float* pa = a + xA;
#define S12_ITER(M)                                                         \
        do {                                                                \
            const f16x8 GH = frag_cast(pG[(M) * 128]);                      \
            const f16x8 GL = frag_cast(pG[(M) * 128 + 64]);                 \
            const f16x8 MH = frag_cast(pM[(M) * 128]);                      \
            const f16x8 ML = frag_cast(pM[(M) * 128 + 64]);                 \
            const float ae = pa[(2 * (M)) * NX];                            \
            const float ao = pa[(2 * (M) + 1) * NX];                        \
            f32x16 C = __builtin_amdgcn_mfma_f32_32x32x16_f16(GH, hH, Z0, 0, 0, 0); \
            C = __builtin_amdgcn_mfma_f32_32x32x16_f16(GH, hL, C, 0, 0, 0); \
            C = __builtin_amdgcn_mfma_f32_32x32x16_f16(GL, hH, C, 0, 0, 0); \
            float se = 0.f, so = 0.f;                                       \
            _Pragma("unroll")                                               \
            for (int r = 0; r < 8; ++r) {                                   \
                se += hC[r] * C[r];                                         \
                so += hC[r] * C[r + 8];                                     \
            }                                                               \
            se += __shfl_xor(se, 32);                                       \
            so += __shfl_xor(so, 32);                                       \
            const float pe = ae * sqrt_act(se);                             \
            const float po = ao * sqrt_act(so);                             \
            f32x16 U = __builtin_amdgcn_mfma_f32_32x32x16_f16(MH, hH, Z0, 0, 0, 0); \
            U = __builtin_amdgcn_mfma_f32_32x32x16_f16(MH, hL, U, 0, 0, 0); \
            U = __builtin_amdgcn_mfma_f32_32x32x16_f16(ML, hH, U, 0, 0, 0); \
            _Pragma("unroll")                                               \
            for (int r = 0; r < 8; ++r)                                     \
                b2[r] += pe * U[r] + po * U[r + 8];                         \
        } while (0)
        S12_ITER(0); S12_ITER(1); S12_ITER(2); S12_ITER(3);
        S12_ITER(4); S12_ITER(5); S12_ITER(6); S12_ITER(7);
#undef S12_ITER
    }

    // ---- b2 cross-group exchange (VERIFIED R21/R22) + f16 hi/lo pack ----
    f16x8 bH, bL;
#define BX(R)                                                               \
    {                                                                       \
        const float snd = g0 ? b2[(R) + 4] : b2[R];                         \
        const float rcv = __shfl_xor(snd, 32);                              \
        const float v0 = g0 ? b2[R] : rcv;          /* pack slot j=R   */   \
        const float v1 = g0 ? rcv : b2[(R) + 4];    /* pack slot j=R+4 */   \
        _Float16 hv = (_Float16)v0;                                         \
        bH[R] = hv;       bL[R]       = (_Float16)(v0 - (float)hv);         \
        hv = (_Float16)v1;                                                  \
        bH[(R) + 4] = hv; bL[(R) + 4] = (_Float16)(v1 - (float)hv);         \
    }
    BX(0) BX(1) BX(2) BX(3)
#undef BX

    // ======== stage 3 (T-pairs), MACRO-EXPANDED:
    //   y += w[T,x] * ( X^T (M2[c,T] . b2) ); ^32-reduce deferred.
    float ya = 0.f;
    {
        const uint4* p2 = AFM2 + (c * 8) * 128 + lane;
        const float* pw = w + xA;
#define S3_ITER(M)                                                          \
        do {                                                                \
            const f16x8 MH = frag_cast(p2[(M) * 128]);                      \
            const f16x8 ML = frag_cast(p2[(M) * 128 + 64]);                 \
            const float we = pw[(2 * (M)) * NX];                            \
            const float wo = pw[(2 * (M) + 1) * NX];                        \
            f32x16 Z = __builtin_amdgcn_mfma_f32_32x32x16_f16(MH, bH, Z0, 0, 0, 0); \
            Z = __builtin_amdgcn_mfma_f32_32x32x16_f16(MH, bL, Z, 0, 0, 0); \
            Z = __builtin_amdgcn_mfma_f32_32x32x16_f16(ML, bH, Z, 0, 0, 0); \
            float se = 0.f, so = 0.f;                                       \
            _Pragma("unroll")                                               \
            for (int r = 0; r < 8; ++r) {                                   \
                se += XC[r] * Z[r];                                         \
                so += XC[r] * Z[r + 8];                                     \
            }                                                               \
            ya += we * se + wo * so;                                        \
        } while (0)
        S3_ITER(0); S3_ITER(1); S3_ITER(2); S3_ITER(3);
        S3_ITER(4); S3_ITER(5); S3_ITER(6); S3_ITER(7);
#undef S3_ITER
    }

    // ---- reduce: ^32 once (deferred), then the 32 columns, then block ----
    float y = ya + __shfl_xor(ya, 32);
    y += __shfl_xor(y, 1); y += __shfl_xor(y, 2);
    y += __shfl_xor(y, 4); y += __shfl_xor(y, 8); y += __shfl_xor(y, 16);
    if (lane == 0) red[wid] = y;
    __syncthreads();
    if (tid == 0) {
        atomicAdd(&out[bp * NC + c], red[0] + red[1] + red[2] + red[3]);
    }
}

extern "C" void kernel_launch(void* const* d_in, const int* in_sizes, int n_in,
                              void* d_out, int out_size, void* d_ws, size_t ws_size,
                              hipStream_t stream) {
    const float* x   = (const float*)d_in[0];
    const float* K0  = (const float*)d_in[1];
    const float* Q0  = (const float*)d_in[2];
    const float* V0  = (const float*)d_in[3];
    const float* K1  = (const float*)d_in[4];
    const float* Q1  = (const float*)d_in[5];
    const float* V1  = (const float*)d_in[6];
    const float* enc = (const float*)d_in[7];
    const float* dec = (const float*)d_in[8];
    const float* a   = (const float*)d_in[9];
    const float* w   = (const float*)d_in[10];
    float* out = (float*)d_out;

    // Pair-frag tables (128 uint4 per pair: [hi 64][lo 64]); contiguous.
    uint4* AF0  = (uint4*)d_ws;              // 256 pairs * 128 = 32768 (512KB)
    uint4* AFG1 = AF0  + 256 * 128;          // 8 pairs   (16KB)
    uint4* AFM1 = AFG1 + 8 * 128;            // 8 pairs   (16KB)
    uint4* AFM2 = AFM1 + 8 * 128;            // 256 pairs (512KB)
    // total ws ~= 1.06 MB

    // out zeroing folded into precompute block 792 (same-stream ordering).
    precompute_all<<<793, 256, 0, stream>>>(K0, V0, K1, V1, Q0, Q1,
                                            enc, dec, AF0, AFG1, AFM1, AFM2,
                                            out);

    const int nblocks = NB * NP * NC * (NX / 128);  // 8*32*16 = 4096
    site_kernel<<<nblocks, 256, 0, stream>>>(x, a, w, AF0, AFG1, AFM1, AFM2, out);
}

// Round 15
// 162.796 us; speedup vs baseline: 1.5430x; 1.5430x over previous
//
#include <hip/hip_runtime.h>
#include <math.h>

// Problem constants (reference: B,P,NTIME,NLATENT,NSPATIAL = 4,2,16,32,2048)
#define NB 4
#define NP 2
#define NT 16
#define NC 32
#define NX 2048

// ---------------------------------------------------------------------------
// R26 = R22 VERBATIM (session best: 163.4us total, 87us site, absmax
// 2.4e-7). Re-anchor after three mapped regressions from this point:
//  - R23 1-wave blocks: 87->130us (workgroup-slot burn, Occ 28->19%)
//  - R24 explicit frag prefetch: 87->93us (live ranges; compiler already
//    schedules loads)
//  - R25 full macro-expansion of stages 1+2/3: 87->170us+ (live-range
//    explosion -> 345MB scratch spills under the VGPR cap)
// The R22 basin: stage 0 macro-expanded (register-h, literal idx), stages
// 1+2/3 unroll-1 pointer-walk, 4-wave blocks, no prefetch, LDS=red[16B].
// Engine: 32x32x16 MFMA, stacked e-pairs, 3-MFMA split (MhVh+MhVl+MlVh;
// MlVl < 2^-24 — absmax-verified no-op). C-layout HW-verified:
// col=lane&31, row=(reg&3)+8(reg>>2)+4(lane>>5) [m74/m101].
// Ledger: readlane=VALU-bound(R11); s_load=latency-bound(R13); LDS
// broadcast=DS-bound(R15); aliased permlane32_swap=WRONG(R17); unroll-
// pragma outer-idx arrays=PROMOTED->macro literal(R21/R22); 1-wave blocks=
// occupancy-poison(R23); frag prefetch=NEGATIVE(R24); >1-iter expansion=
// spill(R25); total-site gap ~76us = fixed overhead+precompute floor.
// Next levers require disasm evidence (accvgpr-mov count, pk_fma), not
// scheduling knobs.
// ---------------------------------------------------------------------------

typedef _Float16 f16x8 __attribute__((ext_vector_type(8)));
typedef float f32x16 __attribute__((ext_vector_type(16)));

__device__ __forceinline__ unsigned short f16hi_bits(float v) {
    _Float16 h = (_Float16)v;
    return __builtin_bit_cast(unsigned short, h);
}
__device__ __forceinline__ unsigned short f16lo_bits(float v) {
    _Float16 h = (_Float16)v;
    _Float16 l = (_Float16)(v - (float)h);
    return __builtin_bit_cast(unsigned short, l);
}
__device__ __forceinline__ f16x8 frag_cast(uint4 u) {
    return __builtin_bit_cast(f16x8, u);
}
__device__ __forceinline__ float sqrt_act(float v) {
    const float s = __builtin_amdgcn_sqrtf(__builtin_fabsf(v));
    return copysignf(s, v);
}
__device__ __forceinline__ f32x16 zero16() {
    f32x16 z;
#pragma unroll
    for (int i = 0; i < 16; ++i) z[i] = 0.f;
    return z;
}

// ---------------------------------------------------------------------------
// Precompute (R21/R22, validated). Pair-frag: pair m holds A-rows 0-15 =
// matrix 2m, 16-31 = matrix 2m+1; 128 uint4 = [hi 64][lo 64]; lane:
// row=lane&31, k=(lane>>5)*8+j.
//  blocks [0,512)   : G0, one e per block (c=b>>4, e=b&15)
//  blocks [512,528) : G1, one e per block
//  blocks [528,536) : M1t pairs (dec+Q1 LDS-staged)
//  blocks [536,792) : M2 pairs  (dec+Q0-col LDS-staged)
//  block  792       : zero out[256]
// ---------------------------------------------------------------------------
__device__ void g_compute(const float* __restrict__ K,
                          const float* __restrict__ V,
                          const float* __restrict__ enc,
                          int cstride, int c, int e, int tid,
                          float* sK, float* sV, float* sE, float* sW,
                          float* outG) {
    {
        const int t = tid >> 4, A = tid & 15;
        sK[tid] = K[(t * 16 + A) * cstride + c];
        sV[tid] = V[(t * 16 + A) * cstride + c];
        sE[tid] = enc[(e * 16 + t) * 16 + A];
    }
    __syncthreads();
    {   // W[t,B] = sum_T enc[e,t,T] * V[T,B,c]
        const int t = tid >> 4, Bi = tid & 15;
        float acc = 0.f;
#pragma unroll
        for (int T = 0; T < 16; ++T) acc += sE[t * 16 + T] * sV[T * 16 + Bi];
        sW[tid] = acc;
    }
    __syncthreads();
    {   // G[A,B] = sum_t K[t,A,c] * W[t,B]   (quadratic form: orientation-immune)
        const int A = tid >> 4, Bi = tid & 15;
        float acc = 0.f;
#pragma unroll
        for (int t = 0; t < 16; ++t) acc += sK[t * 16 + A] * sW[t * 16 + Bi];
        outG[tid] = acc;
    }
    __syncthreads();
}

__device__ void emit_half(const float* sG, uint4* __restrict__ dstPair,
                          int half, int tid) {
    if (tid < 64) {
        const int row = tid & 15, g = (tid >> 4) & 1, part = tid >> 5;
        unsigned dw[4];
#pragma unroll
        for (int d = 0; d < 4; ++d) {
            const float v0 = sG[row * 16 + g * 8 + 2 * d];
            const float v1 = sG[row * 16 + g * 8 + 2 * d + 1];
            const unsigned short s0 = part ? f16lo_bits(v0) : f16hi_bits(v0);
            const unsigned short s1 = part ? f16lo_bits(v1) : f16hi_bits(v1);
            dw[d] = (unsigned)s0 | ((unsigned)s1 << 16);
        }
        dstPair[part * 64 + g * 32 + 16 * half + row] =
            make_uint4(dw[0], dw[1], dw[2], dw[3]);
    }
}

__global__ __launch_bounds__(256) void precompute_all(
    const float* __restrict__ K0, const float* __restrict__ V0,
    const float* __restrict__ K1, const float* __restrict__ V1,
    const float* __restrict__ Q0, const float* __restrict__ Q1,
    const float* __restrict__ enc, const float* __restrict__ dec,
    uint4* __restrict__ AF0, uint4* __restrict__ AFG1,
    uint4* __restrict__ AFM1, uint4* __restrict__ AFM2,
    float* __restrict__ out) {
    __shared__ float sK[256], sV[256], sE[256], sW[256], sG[256];
    __shared__ float sDec[4096], sQ[256];
    const int b = blockIdx.x, tid = threadIdx.x;
    if (b < 512) {
        const int c = b >> 4, e = b & 15;
        g_compute(K0, V0, enc, NC, c, e, tid, sK, sV, sE, sW, sG);
        emit_half(sG, AF0 + (c * 8 + (e >> 1)) * 128, e & 1, tid);
    } else if (b < 528) {
        const int e = b - 512;
        g_compute(K1, V1, enc, 1, 0, e, tid, sK, sV, sE, sW, sG);
        emit_half(sG, AFG1 + (e >> 1) * 128, e & 1, tid);
    } else if (b < 536) {
        // M1t[e][E][T] = sum_t Q1[t,T]*dec[e,t,E]; pair rows=E, k=T
        const int m = b - 528;
#pragma unroll
        for (int i = tid; i < 4096; i += 256) sDec[i] = dec[i];
        sQ[tid] = Q1[tid];
        __syncthreads();
        if (tid < 128) {
            const int part = tid >> 6, lane = tid & 63;
            const int row32 = lane & 31, g = lane >> 5;
            const int e = 2 * m + (row32 >> 4), E = row32 & 15;
            unsigned dw[4];
#pragma unroll
            for (int d = 0; d < 4; ++d) {
                unsigned short s01[2];
#pragma unroll
                for (int hh = 0; hh < 2; ++hh) {
                    const int T = g * 8 + 2 * d + hh;
                    float acc = 0.f;
#pragma unroll
                    for (int t = 0; t < 16; ++t)
                        acc += sQ[t * 16 + T] * sDec[(e * 16 + t) * 16 + E];
                    s01[hh] = part ? f16lo_bits(acc) : f16hi_bits(acc);
                }
                dw[d] = (unsigned)s01[0] | ((unsigned)s01[1] << 16);
            }
            AFM1[m * 128 + part * 64 + lane] = make_uint4(dw[0], dw[1], dw[2], dw[3]);
        }
    } else if (b < 792) {
        // M2[c][T][A][E] = sum_t Q0[t,A,c]*dec[E,t,T]; pair rows=A (T-pair), k=E
        const int idx = b - 536;
        const int c = idx >> 3, m = idx & 7;
#pragma unroll
        for (int i = tid; i < 4096; i += 256) sDec[i] = dec[i];
        sQ[tid] = Q0[tid * NC + c];            // tid = t*16+A
        __syncthreads();
        if (tid < 128) {
            const int part = tid >> 6, lane = tid & 63;
            const int row32 = lane & 31, g = lane >> 5;
            const int T = 2 * m + (row32 >> 4), A = row32 & 15;
            unsigned dw[4];
#pragma unroll
            for (int d = 0; d < 4; ++d) {
                unsigned short s01[2];
#pragma unroll
                for (int hh = 0; hh < 2; ++hh) {
                    const int E = g * 8 + 2 * d + hh;
                    float acc = 0.f;
#pragma unroll
                    for (int t = 0; t < 16; ++t)
                        acc += sQ[t * 16 + A] * sDec[(E * 16 + t) * 16 + T];
                    s01[hh] = part ? f16lo_bits(acc) : f16hi_bits(acc);
                }
                dw[d] = (unsigned)s01[0] | ((unsigned)s01[1] << 16);
            }
            AFM2[(c * 8 + m) * 128 + part * 64 + lane] =
                make_uint4(dw[0], dw[1], dw[2], dw[3]);
        }
    } else {
        out[tid] = 0.f;   // out = NB*NP*NC = 256 floats
    }
}

// ---------------------------------------------------------------------------
// Main kernel: 4 waves/block (256 thr), one wave = 32 x-sites (col=lane&31)
// of one (bp,c). grid = 4096; consecutive blocks share (bp,c) -> frag
// tables L2/L1-hot. h lives in REGISTERS: stage 0 macro-expanded with
// literal h[] indices (SROA-scalarizable, rule #20). Stages 1+2/3 are
// unroll-1 pointer-walk bodies (no prefetch — R24). LDS = red[16B] only.
// ---------------------------------------------------------------------------
__global__ __launch_bounds__(256) void site_kernel(
    const float* __restrict__ x,
    const float* __restrict__ a,
    const float* __restrict__ w,
    const uint4* __restrict__ AF0,
    const uint4* __restrict__ AFG1,
    const uint4* __restrict__ AFM1,
    const uint4* __restrict__ AFM2,
    float* __restrict__ out) {
    __shared__ float red[4];

    const int tid = threadIdx.x;
    const int lane = tid & 63, wid = tid >> 6;
    const int col = lane & 31, g = lane >> 5;
    const bool g0 = (g == 0);
    const int bid = blockIdx.x;
    const int xg = bid & 15;
    const int c  = (bid >> 4) & 31;
    const int bp = bid >> 9;
    const int xA = xg * 128 + wid * 32 + col;
    const float* xb = x + (bp * NT * NC + c) * NX;

    // ---- X: B-pack k-rows g*8+j (f16 hi/lo) + C-rows A(r)=(r&3)+8(r>>2)+4g ----
    f16x8 Xh, Xl;
    float XC[8];
#pragma unroll
    for (int j = 0; j < 8; ++j) {
        const float v = xb[(g * 8 + j) * NC * NX + xA];
        const _Float16 hv = (_Float16)v;
        Xh[j] = hv; Xl[j] = (_Float16)(v - (float)hv);
    }
#pragma unroll
    for (int r = 0; r < 8; ++r) {
        const int A = (r & 3) + 8 * (r >> 2) + 4 * g;
        XC[r] = xb[A * NC * NX + xA];
    }

    const f32x16 Z0 = zero16();    // shared accumulator-zero (one init)

    // ======== stage 0: h[e] = sqrt_act( X^T G0[c,e] X ), e-pairs ========
    // Macro-expanded: every h[] index is a LITERAL -> SROA keeps h in VGPRs.
    float h[16];
    {
        const uint4* p0 = AF0 + (c * 8) * 128 + lane;
#define S0_ITER(M)                                                          \
        do {                                                                \
            const f16x8 Ah = frag_cast(p0[(M) * 128]);                      \
            const f16x8 Al = frag_cast(p0[(M) * 128 + 64]);                 \
            f32x16 C = __builtin_amdgcn_mfma_f32_32x32x16_f16(Ah, Xh, Z0, 0, 0, 0); \
            C = __builtin_amdgcn_mfma_f32_32x32x16_f16(Ah, Xl, C, 0, 0, 0); \
            C = __builtin_amdgcn_mfma_f32_32x32x16_f16(Al, Xh, C, 0, 0, 0); \
            float se = 0.f, so = 0.f;                                       \
            _Pragma("unroll")                                               \
            for (int r = 0; r < 8; ++r) {                                   \
                se += XC[r] * C[r];                                         \
                so += XC[r] * C[r + 8];                                     \
            }                                                               \
            se += __shfl_xor(se, 32);                                       \
            so += __shfl_xor(so, 32);                                       \
            h[2 * (M)]     = sqrt_act(se);                                  \
            h[2 * (M) + 1] = sqrt_act(so);                                  \
        } while (0)
        S0_ITER(0); S0_ITER(1); S0_ITER(2); S0_ITER(3);
        S0_ITER(4); S0_ITER(5); S0_ITER(6); S0_ITER(7);
#undef S0_ITER
    }

    // ---- h packs from registers: literal indices via macro expansion ----
    f16x8 hH, hL;
    float hC[8];
#define HPK(J)                                                              \
    {                                                                       \
        const float v = g0 ? h[J] : h[(J) + 8];        /* k = g*8+J */      \
        const _Float16 hv = (_Float16)v;                                    \
        hH[J] = hv; hL[J] = (_Float16)(v - (float)hv);                      \
    }
    HPK(0) HPK(1) HPK(2) HPK(3) HPK(4) HPK(5) HPK(6) HPK(7)
#undef HPK
#define HCK(R, BASE) hC[R] = g0 ? h[BASE] : h[(BASE) + 4];
    HCK(0, 0) HCK(1, 1) HCK(2, 2) HCK(3, 3)
    HCK(4, 8) HCK(5, 9) HCK(6, 10) HCK(7, 11)
#undef HCK

    // ======== stages 1+2 (e-pairs): pe = a[e,x]*sqrt_act(h^T G1[e] h);
    //   b2[E] += pe_even*U_even[E] + pe_odd*U_odd[E], U = M1t-pair . h
    float b2[8];
#pragma unroll
    for (int r = 0; r < 8; ++r) b2[r] = 0.f;
    {
        const uint4* pG = AFG1 + lane;
        const uint4* pM = AFM1 + lane;
        const float* pa = a + xA;
#pragma unroll 1
        for (int m = 0; m < 8; ++m) {
            const f16x8 GH = frag_cast(pG[0]);
            const f16x8 GL = frag_cast(pG[64]);
            const f16x8 MH = frag_cast(pM[0]);
            const f16x8 ML = frag_cast(pM[64]);
            pG += 128; pM += 128;
            const float ae = pa[0], ao = pa[NX];
            pa += 2 * NX;
            f32x16 C = __builtin_amdgcn_mfma_f32_32x32x16_f16(GH, hH, Z0, 0, 0, 0);
            C = __builtin_amdgcn_mfma_f32_32x32x16_f16(GH, hL, C, 0, 0, 0);
            C = __builtin_amdgcn_mfma_f32_32x32x16_f16(GL, hH, C, 0, 0, 0);
            float se = 0.f, so = 0.f;
#pragma unroll
            for (int r = 0; r < 8; ++r) {
                se += hC[r] * C[r];
                so += hC[r] * C[r + 8];
            }
            se += __shfl_xor(se, 32);
            so += __shfl_xor(so, 32);
            const float pe = ae * sqrt_act(se);
            const float po = ao * sqrt_act(so);
            f32x16 U = __builtin_amdgcn_mfma_f32_32x32x16_f16(MH, hH, Z0, 0, 0, 0);
            U = __builtin_amdgcn_mfma_f32_32x32x16_f16(MH, hL, U, 0, 0, 0);
            U = __builtin_amdgcn_mfma_f32_32x32x16_f16(ML, hH, U, 0, 0, 0);
#pragma unroll
            for (int r = 0; r < 8; ++r)
                b2[r] += pe * U[r] + po * U[r + 8];
        }
    }

    // ---- b2 cross-group exchange (VERIFIED R21/R22) + f16 hi/lo pack ----
    f16x8 bH, bL;
#define BX(R)                                                               \
    {                                                                       \
        const float snd = g0 ? b2[(R) + 4] : b2[R];                         \
        const float rcv = __shfl_xor(snd, 32);                              \
        const float v0 = g0 ? b2[R] : rcv;          /* pack slot j=R   */   \
        const float v1 = g0 ? rcv : b2[(R) + 4];    /* pack slot j=R+4 */   \
        _Float16 hv = (_Float16)v0;                                         \
        bH[R] = hv;       bL[R]       = (_Float16)(v0 - (float)hv);         \
        hv = (_Float16)v1;                                                  \
        bH[(R) + 4] = hv; bL[(R) + 4] = (_Float16)(v1 - (float)hv);         \
    }
    BX(0) BX(1) BX(2) BX(3)
#undef BX

    // ======== stage 3 (T-pairs): y += w[T,x] * ( X^T (M2[c,T] . b2) ) ========
    // ^32-reduce deferred out of the loop (w identical for lane and lane^32).
    float ya = 0.f;
    {
        const uint4* p2 = AFM2 + (c * 8) * 128 + lane;
        const float* pw = w + xA;
#pragma unroll 1
        for (int m = 0; m < 8; ++m) {
            const f16x8 MH = frag_cast(p2[0]);
            const f16x8 ML = frag_cast(p2[64]);
            p2 += 128;
            const float we = pw[0], wo = pw[NX];
            pw += 2 * NX;
            f32x16 Z = __builtin_amdgcn_mfma_f32_32x32x16_f16(MH, bH, Z0, 0, 0, 0);
            Z = __builtin_amdgcn_mfma_f32_32x32x16_f16(MH, bL, Z, 0, 0, 0);
            Z = __builtin_amdgcn_mfma_f32_32x32x16_f16(ML, bH, Z, 0, 0, 0);
            float se = 0.f, so = 0.f;
#pragma unroll
            for (int r = 0; r < 8; ++r) {
                se += XC[r] * Z[r];
                so += XC[r] * Z[r + 8];
            }
            ya += we * se + wo * so;
        }
    }

    // ---- reduce: ^32 once (deferred), then the 32 columns, then block ----
    float y = ya + __shfl_xor(ya, 32);
    y += __shfl_xor(y, 1); y += __shfl_xor(y, 2);
    y += __shfl_xor(y, 4); y += __shfl_xor(y, 8); y += __shfl_xor(y, 16);
    if (lane == 0) red[wid] = y;
    __syncthreads();
    if (tid == 0) {
        atomicAdd(&out[bp * NC + c], red[0] + red[1] + red[2] + red[3]);
    }
}

extern "C" void kernel_launch(void* const* d_in, const int* in_sizes, int n_in,
                              void* d_out, int out_size, void* d_ws, size_t ws_size,
                              hipStream_t stream) {
    const float* x   = (const float*)d_in[0];
    const float* K0  = (const float*)d_in[1];
    const float* Q0  = (const float*)d_in[2];
    const float* V0  = (const float*)d_in[3];
    const float* K1  = (const float*)d_in[4];
    const float* Q1  = (const float*)d_in[5];
    const float* V1  = (const float*)d_in[6];
    const float* enc = (const float*)d_in[7];
    const float* dec = (const float*)d_in[8];
    const float* a   = (const float*)d_in[9];
    const float* w   = (const float*)d_in[10];
    float* out = (float*)d_out;

    // Pair-frag tables (128 uint4 per pair: [hi 64][lo 64]); contiguous.
    uint4* AF0  = (uint4*)d_ws;              // 256 pairs * 128 = 32768 (512KB)
    uint4* AFG1 = AF0  + 256 * 128;          // 8 pairs   (16KB)
    uint4* AFM1 = AFG1 + 8 * 128;            // 8 pairs   (16KB)
    uint4* AFM2 = AFM1 + 8 * 128;            // 256 pairs (512KB)
    // total ws ~= 1.06 MB

    // out zeroing folded into precompute block 792 (same-stream ordering).
    precompute_all<<<793, 256, 0, stream>>>(K0, V0, K1, V1, Q0, Q1,
                                            enc, dec, AF0, AFG1, AFM1, AFM2,
                                            out);

    const int nblocks = NB * NP * NC * (NX / 128);  // 8*32*16 = 4096
    site_kernel<<<nblocks, 256, 0, stream>>>(x, a, w, AF0, AFG1, AFM1, AFM2, out);
}